// Round 2
// baseline (936.903 us; speedup 1.0000x reference)
//
#include <hip/hip_runtime.h>
#include <hip/hip_bf16.h>

// Problem constants (from reference)
#define T_TOK 4096      // SL*BS tokens
#define E_EXP 16
#define TOPK 4
#define HDIM 1024
#define FDIM 2048
#define CAP 1024        // capacity = K*T/E
#define NCOPY (T_TOK*TOPK)

typedef __bf16 bf16x8 __attribute__((ext_vector_type(8)));
typedef __bf16 bf16x4 __attribute__((ext_vector_type(4)));
typedef float  f32x4  __attribute__((ext_vector_type(4)));

// Async global->LDS, 16B per lane. LDS dest must be wave-uniform base + lane*16
// (m104/m108): our mapping lds = base + tid*16 satisfies this exactly.
__device__ __forceinline__ void async16(const __bf16* g, __bf16* l)
{
    __builtin_amdgcn_global_load_lds(
        (const __attribute__((address_space(1))) unsigned int*)g,
        (__attribute__((address_space(3))) unsigned int*)l,
        16, 0, 0);
}

// ---------------------------------------------------------------------------
// Router: logits = x @ rw^T + rb ; top-4 (desc, ties->lowest idx) ; softmax.
// One wave per token. Writes expert_weights [T,4], router_scores [E,T], te [T,4].
// ---------------------------------------------------------------------------
__global__ __launch_bounds__(64) void router_kernel(
    const float* __restrict__ x, const float* __restrict__ rw, const float* __restrict__ rb,
    float* __restrict__ ew_out, float* __restrict__ rs_out, int* __restrict__ te_out)
{
    int t = blockIdx.x;
    int lane = threadIdx.x;
    const float* xr = x + (size_t)t * HDIM;
    float xv[16];
#pragma unroll
    for (int i = 0; i < 16; ++i) xv[i] = xr[i * 64 + lane];
    float lg[E_EXP];
#pragma unroll
    for (int e = 0; e < E_EXP; ++e) {
        const float* wrow = rw + (size_t)e * HDIM;
        float s = 0.f;
#pragma unroll
        for (int i = 0; i < 16; ++i) s += xv[i] * wrow[i * 64 + lane];
#pragma unroll
        for (int off = 32; off > 0; off >>= 1) s += __shfl_xor(s, off, 64);
        lg[e] = s + rb[e];
    }
    int mask = 0; float vals[4]; int idxs[4];
#pragma unroll
    for (int k = 0; k < 4; ++k) {
        float m = -3.4e38f; int a = 0;
#pragma unroll
        for (int e = 0; e < E_EXP; ++e) {
            bool take = (((mask >> e) & 1) == 0) && (lg[e] > m);
            m = take ? lg[e] : m;
            a = take ? e : a;
        }
        vals[k] = m; idxs[k] = a; mask |= (1 << a);
    }
    float wk[4]; float ssum = 0.f;
#pragma unroll
    for (int k = 0; k < 4; ++k) { wk[k] = __expf(vals[k] - vals[0]); ssum += wk[k]; }
    float inv = 1.f / ssum;
#pragma unroll
    for (int k = 0; k < 4; ++k) wk[k] *= inv;
    if (lane < 4) {
        float wv = 0.f; int iv = 0;
#pragma unroll
        for (int k = 0; k < 4; ++k) if (lane == k) { wv = wk[k]; iv = idxs[k]; }
        ew_out[t * 4 + lane] = wv;
        te_out[t * 4 + lane] = iv;
    }
    if (lane < E_EXP) {
        float v = 0.f;
#pragma unroll
        for (int k = 0; k < 4; ++k) v = (idxs[k] == lane) ? wk[k] : v;
        rs_out[(size_t)lane * T_TOK + t] = v;
    }
}

// ---------------------------------------------------------------------------
// Binning: stable rank-within-expert == stable argsort by expert id.
// Also emits copy->slot map (slot_of) for the gather-combine epilogue.
// ---------------------------------------------------------------------------
__global__ __launch_bounds__(256) void binning_kernel(
    const int* __restrict__ te,
    int* __restrict__ slot_tok, int* __restrict__ slot_of)
{
    __shared__ int cnt[256][17];   // +1 pad: conflict-free columns
    int tid = threadIdx.x;
#pragma unroll
    for (int e = 0; e < E_EXP; ++e) cnt[tid][e] = 0;
    __syncthreads();
    int base = tid * 64;
    for (int i = 0; i < 64; ++i) cnt[tid][te[base + i]]++;
    __syncthreads();
    if (tid < E_EXP) {
        int run = 0;
        for (int t2 = 0; t2 < 256; ++t2) { int v = cnt[t2][tid]; cnt[t2][tid] = run; run += v; }
    }
    __syncthreads();
    for (int s = tid; s < E_EXP * CAP; s += 256) slot_tok[s] = -1;
    __syncthreads();
    for (int i = 0; i < 64; ++i) {
        int idx = base + i;
        int e = te[idx];
        int r = cnt[tid][e]; cnt[tid][e] = r + 1;
        if (r < CAP) { slot_tok[e * CAP + r] = idx >> 2; slot_of[idx] = e * CAP + r; }
        else slot_of[idx] = -1;
    }
}

// ---------------------------------------------------------------------------
// Gather: xg[e][c][:] = bf16(x[tok]) or zeros. One block per slot.
// ---------------------------------------------------------------------------
__global__ __launch_bounds__(256) void gather_kernel(
    const float* __restrict__ x, const int* __restrict__ slot_tok, __bf16* __restrict__ xg)
{
    int s = blockIdx.x, tid = threadIdx.x;
    int tok = slot_tok[s];
    bf16x4 o;
    if (tok >= 0) {
        float4 v = *(const float4*)(x + (size_t)tok * HDIM + tid * 4);
        o[0] = (__bf16)v.x; o[1] = (__bf16)v.y; o[2] = (__bf16)v.z; o[3] = (__bf16)v.w;
    } else {
        o[0] = (__bf16)0.f; o[1] = (__bf16)0.f; o[2] = (__bf16)0.f; o[3] = (__bf16)0.f;
    }
    *(bf16x4*)(xg + (size_t)s * HDIM + tid * 4) = o;
}

// ---------------------------------------------------------------------------
// Transpose + fp32->bf16: in [e][R][Cc] -> out [e][Cc][R]. 64x64 LDS tiles.
// ---------------------------------------------------------------------------
__global__ __launch_bounds__(256) void transpose_cvt_kernel(
    const float* __restrict__ in, __bf16* __restrict__ out, int R, int Cc, int tilesR, int tilesC)
{
    __shared__ __bf16 tile[64][68];
    int bx = blockIdx.x;
    int tpe = tilesR * tilesC;
    int e = bx / tpe; int rem = bx - e * tpe;
    int tr = rem / tilesC; int tc = rem - tr * tilesC;
    const float* ine = in + (size_t)e * R * Cc;
    __bf16* oute = out + (size_t)e * R * Cc;
    int r0 = tr * 64, c0 = tc * 64;
    int tid = threadIdx.x;
    int rr = tid >> 4, c4 = (tid & 15) << 2;
#pragma unroll
    for (int it = 0; it < 4; ++it) {
        int r = rr + it * 16;
        float4 v = *(const float4*)(ine + (size_t)(r0 + r) * Cc + c0 + c4);
        tile[r][c4 + 0] = (__bf16)v.x; tile[r][c4 + 1] = (__bf16)v.y;
        tile[r][c4 + 2] = (__bf16)v.z; tile[r][c4 + 3] = (__bf16)v.w;
    }
    __syncthreads();
#pragma unroll
    for (int it = 0; it < 4; ++it) {
        int c = rr + it * 16;
        bf16x4 o;
        o[0] = tile[c4 + 0][c]; o[1] = tile[c4 + 1][c];
        o[2] = tile[c4 + 2][c]; o[3] = tile[c4 + 3][c];
        *(bf16x4*)(oute + (size_t)(c0 + c) * R + r0 + c4) = o;
    }
}

// ---------------------------------------------------------------------------
// GEMM (m97-style): A [e][1024][Kd] bf16 k-contig, Bt [e][N][Kd] bf16 k-contig.
// 128x128 tile, BK=32, 4 waves, 4x4 mfma_f32_16x16x32_bf16 per wave.
// global_load_lds width-16 staging, 2-barrier K-loop (m97 verified structure).
// EPI 0: bias + interleaved GLU -> act bf16 [e][1024][FDIM]
// EPI 1: bias -> y bf16 [e][1024][HDIM] (combined later, no atomics)
// ---------------------------------------------------------------------------
template <int EPI>
__global__ __launch_bounds__(256) void gemm_kernel(
    const __bf16* __restrict__ A, const __bf16* __restrict__ Bt, const float* __restrict__ bias,
    __bf16* __restrict__ outp, int Kd, int tilesM, int tilesN, int N)
{
    __shared__ __bf16 at[128 * 32];
    __shared__ __bf16 bts[128 * 32];
    int bx = blockIdx.x;
    int tpe = tilesM * tilesN;
    int e = bx / tpe; int rem = bx - e * tpe;
    int bm = rem / tilesN; int bn = rem - bm * tilesN;
    const __bf16* Ab = A + (size_t)e * 1024 * Kd + (size_t)(bm * 128) * Kd;
    const __bf16* Bb = Bt + (size_t)e * N * Kd + (size_t)(bn * 128) * Kd;
    int tid = threadIdx.x;
    int c0 = tid, c1 = tid + 256;
    int ar0 = c0 >> 2, ak0 = (c0 & 3) << 3;
    int ar1 = c1 >> 2, ak1 = (c1 & 3) << 3;

    const __bf16* gA0 = Ab + (size_t)ar0 * Kd + ak0;
    const __bf16* gA1 = Ab + (size_t)ar1 * Kd + ak1;
    const __bf16* gB0 = Bb + (size_t)ar0 * Kd + ak0;
    const __bf16* gB1 = Bb + (size_t)ar1 * Kd + ak1;
    __bf16* lA0 = at + c0 * 8;
    __bf16* lA1 = at + c1 * 8;
    __bf16* lB0 = bts + c0 * 8;
    __bf16* lB1 = bts + c1 * 8;

    f32x4 zero4 = {0.f, 0.f, 0.f, 0.f};
    f32x4 acc[4][4];
#pragma unroll
    for (int mi = 0; mi < 4; ++mi)
#pragma unroll
        for (int ni = 0; ni < 4; ++ni) acc[mi][ni] = zero4;

    int w = tid >> 6, l = tid & 63;
    int q = l >> 4, ln = l & 15;
    int wr = (w >> 1) << 6, wc = (w & 1) << 6;

    for (int k0 = 0; k0 < Kd; k0 += 32) {
        async16(gA0 + k0, lA0);
        async16(gA1 + k0, lA1);
        async16(gB0 + k0, lB0);
        async16(gB1 + k0, lB1);
        __syncthreads();   // compiler emits vmcnt(0) drain here -> data visible
        bf16x8 af[4], bfr[4];
#pragma unroll
        for (int mi = 0; mi < 4; ++mi)
            af[mi] = *(const bf16x8*)(at + (wr + mi * 16 + ln) * 32 + q * 8);
#pragma unroll
        for (int ni = 0; ni < 4; ++ni)
            bfr[ni] = *(const bf16x8*)(bts + (wc + ni * 16 + ln) * 32 + q * 8);
#pragma unroll
        for (int mi = 0; mi < 4; ++mi)
#pragma unroll
            for (int ni = 0; ni < 4; ++ni)
                acc[mi][ni] = __builtin_amdgcn_mfma_f32_16x16x32_bf16(af[mi], bfr[ni], acc[mi][ni], 0, 0, 0);
        __syncthreads();   // all reads done before next k-step overwrites LDS
    }

    // C/D layout: col = lane&15, row = (lane>>4)*4 + reg   [m89-verified]
    float bv[4];
#pragma unroll
    for (int ni = 0; ni < 4; ++ni) bv[ni] = bias[(size_t)e * N + bn * 128 + wc + ni * 16 + ln];

    if constexpr (EPI == 0) {
        __bf16* act_e = outp + (size_t)e * 1024 * FDIM;
#pragma unroll
        for (int mi = 0; mi < 4; ++mi)
#pragma unroll
            for (int ni = 0; ni < 4; ++ni)
#pragma unroll
                for (int r = 0; r < 4; ++r) {
                    int m = bm * 128 + wr + mi * 16 + q * 4 + r;
                    int n = bn * 128 + wc + ni * 16 + ln;
                    float v = acc[mi][ni][r] + bv[ni];
                    float o = __shfl_xor(v, 1, 64);        // partner column (n^1)
                    float gate = (ln & 1) ? o : v;          // even col = gate
                    float up   = (ln & 1) ? v : o;          // odd col  = up
                    gate = fminf(gate, 7.f);
                    up = fminf(fmaxf(up, -7.f), 7.f);
                    float glu = gate / (1.f + __expf(-1.702f * gate));
                    float a = (up + 1.f) * glu;
                    if ((ln & 1) == 0) act_e[(size_t)m * FDIM + (n >> 1)] = (__bf16)a;
                }
    } else {
        __bf16* y_e = outp + (size_t)e * 1024 * HDIM;
#pragma unroll
        for (int mi = 0; mi < 4; ++mi)
#pragma unroll
            for (int ni = 0; ni < 4; ++ni)
#pragma unroll
                for (int r = 0; r < 4; ++r) {
                    int m = bm * 128 + wr + mi * 16 + q * 4 + r;
                    int n = bn * 128 + wc + ni * 16 + ln;
                    y_e[(size_t)m * HDIM + n] = (__bf16)(acc[mi][ni][r] + bv[ni]);
                }
    }
}

// ---------------------------------------------------------------------------
// Combine: out[t][:] = sum_k ew[t][k] * y[slot_of[t*4+k]][:]  (skip dropped).
// One block per token; fully coalesced; replaces zero-init + atomics.
// ---------------------------------------------------------------------------
__global__ __launch_bounds__(256) void combine_kernel(
    const __bf16* __restrict__ y, const int* __restrict__ slot_of,
    const float* __restrict__ ew, float* __restrict__ out)
{
    int t = blockIdx.x, tid = threadIdx.x;
    float a0 = 0.f, a1 = 0.f, a2 = 0.f, a3 = 0.f;
#pragma unroll
    for (int k = 0; k < 4; ++k) {
        int s = slot_of[t * 4 + k];
        if (s >= 0) {
            float wk = ew[t * 4 + k];
            bf16x4 v = *(const bf16x4*)(y + (size_t)s * HDIM + tid * 4);
            a0 += wk * (float)v[0]; a1 += wk * (float)v[1];
            a2 += wk * (float)v[2]; a3 += wk * (float)v[3];
        }
    }
    float4 o = make_float4(a0, a1, a2, a3);
    *(float4*)(out + (size_t)t * HDIM + tid * 4) = o;
}

// ---------------------------------------------------------------------------
extern "C" void kernel_launch(void* const* d_in, const int* in_sizes, int n_in,
                              void* d_out, int out_size, void* d_ws, size_t ws_size,
                              hipStream_t stream)
{
    const float* x  = (const float*)d_in[0];
    const float* rw = (const float*)d_in[1];
    const float* rb = (const float*)d_in[2];
    const float* w1 = (const float*)d_in[3];
    const float* w2 = (const float*)d_in[4];
    const float* b1 = (const float*)d_in[5];
    const float* b2 = (const float*)d_in[6];
    float* out_main = (float*)d_out;                       // [T,H]
    float* ew_out = out_main + (size_t)T_TOK * HDIM;       // [T,4]
    float* rs_out = ew_out + (size_t)T_TOK * TOPK;         // [E,T]

    char* ws = (char*)d_ws;
    size_t off = 0;
    auto alloc = [&](size_t bytes) { void* p = ws + off; off += (bytes + 255) & ~(size_t)255; return p; };
    __bf16* w1t = (__bf16*)alloc((size_t)E_EXP * 2 * FDIM * HDIM * 2);  // [E][2F][H] 134MB
    __bf16* w2t = (__bf16*)alloc((size_t)E_EXP * HDIM * FDIM * 2);      // [E][H][F]  67MB
    __bf16* xg  = (__bf16*)alloc((size_t)E_EXP * CAP * HDIM * 2);       // [E][C][H]  33.5MB (reused as y)
    __bf16* act = (__bf16*)alloc((size_t)E_EXP * CAP * FDIM * 2);       // [E][C][F]  67MB
    int*   te       = (int*)alloc((size_t)NCOPY * 4);
    int*   slot_tok = (int*)alloc((size_t)E_EXP * CAP * 4);
    int*   slot_of  = (int*)alloc((size_t)NCOPY * 4);
    __bf16* y = xg;   // xg is dead after GEMM1; reuse for y [E][C][H]

    router_kernel<<<T_TOK, 64, 0, stream>>>(x, rw, rb, ew_out, rs_out, te);
    binning_kernel<<<1, 256, 0, stream>>>(te, slot_tok, slot_of);
    gather_kernel<<<E_EXP * CAP, 256, 0, stream>>>(x, slot_tok, xg);
    transpose_cvt_kernel<<<E_EXP * (HDIM / 64) * (2 * FDIM / 64), 256, 0, stream>>>(
        w1, w1t, HDIM, 2 * FDIM, HDIM / 64, 2 * FDIM / 64);
    transpose_cvt_kernel<<<E_EXP * (FDIM / 64) * (HDIM / 64), 256, 0, stream>>>(
        w2, w2t, FDIM, HDIM, FDIM / 64, HDIM / 64);
    gemm_kernel<0><<<E_EXP * 8 * 32, 256, 0, stream>>>(
        xg, w1t, b1, act, HDIM, 8, 32, 2 * FDIM);
    gemm_kernel<1><<<E_EXP * 8 * 8, 256, 0, stream>>>(
        act, w2t, b2, y, FDIM, 8, 8, HDIM);
    combine_kernel<<<T_TOK, 256, 0, stream>>>(y, slot_of, ew_out, out_main);
}